// Round 2
// baseline (1804.277 us; speedup 1.0000x reference)
//
#include <hip/hip_runtime.h>
#include <math.h>

#define BB 8
#define CC 192
#define NN 3136            // 56*56
#define NR 25088           // BB*NN
#define C2 384
#define GI 96
#define KNN 9
#define NCHUNK 256
#define RPC 98             // 256*98 = 25088
#define EPS_BN 1e-5f

// ---------------- fc1: z[b,n,c] = sum_k x[b,k,n]*w1[c,k] + b1[c] ----------------
__global__ __launch_bounds__(256) void k_fc1(const float* __restrict__ x,
        const float* __restrict__ w1, const float* __restrict__ b1,
        float* __restrict__ z) {
  __shared__ __align__(16) float Xs[32*68];
  __shared__ __align__(16) float Ws[32*68];
  int b = blockIdx.z, n0 = blockIdx.x*64, c0 = blockIdx.y*64;
  int tid = threadIdx.x;
  int tcol = tid & 15, trow = tid >> 4;
  float acc[4][4] = {};
  const float4* xf4 = (const float4*)x;
  const float4* wf4 = (const float4*)w1;
  for (int kb = 0; kb < 6; ++kb) {
    int k0 = kb*32;
    __syncthreads();
    #pragma unroll
    for (int s = 0; s < 2; ++s) {
      int q = tid + 256*s;
      int kk = q >> 4, nq = q & 15;
      ((float4*)Xs)[kk*17 + nq] = xf4[(size_t)(b*CC + k0 + kk)*784 + (n0>>2) + nq];
    }
    #pragma unroll
    for (int s = 0; s < 2; ++s) {
      int q = tid + 256*s;
      int cc = q >> 3, kq = q & 7;
      float4 v = wf4[(size_t)(c0 + cc)*48 + (k0>>2) + kq];
      Ws[(kq*4+0)*68 + cc] = v.x;
      Ws[(kq*4+1)*68 + cc] = v.y;
      Ws[(kq*4+2)*68 + cc] = v.z;
      Ws[(kq*4+3)*68 + cc] = v.w;
    }
    __syncthreads();
    #pragma unroll 8
    for (int kk = 0; kk < 32; ++kk) {
      float4 a4 = ((const float4*)Xs)[kk*17 + trow];
      float4 b4 = ((const float4*)Ws)[kk*17 + tcol];
      float av[4] = {a4.x,a4.y,a4.z,a4.w};
      float bv[4] = {b4.x,b4.y,b4.z,b4.w};
      #pragma unroll
      for (int i = 0; i < 4; ++i)
        #pragma unroll
        for (int j = 0; j < 4; ++j)
          acc[i][j] += av[i]*bv[j];
    }
  }
  float4 bias = ((const float4*)b1)[(c0>>2) + tcol];
  float bb4[4] = {bias.x,bias.y,bias.z,bias.w};
  #pragma unroll
  for (int i = 0; i < 4; ++i) {
    int n = n0 + trow*4 + i;
    float4 o;
    o.x = acc[i][0] + bb4[0]; o.y = acc[i][1] + bb4[1];
    o.z = acc[i][2] + bb4[2]; o.w = acc[i][3] + bb4[3];
    ((float4*)z)[(size_t)(b*NN + n)*48 + (c0>>2) + tcol] = o;
  }
}

// ---------------- BN stats: deterministic 2-stage ----------------
__global__ void k_stats_part(const float* __restrict__ src, int C, float* __restrict__ part) {
  int c = threadIdx.x;        // blockDim.x == C
  int chunk = blockIdx.x;     // 0..255
  float s = 0.f, ss = 0.f;
  const float* p = src + (size_t)chunk*RPC*C + c;
  for (int r = 0; r < RPC; ++r) {
    float v = p[(size_t)r*C];
    s += v; ss += v*v;
  }
  part[(size_t)chunk*C + c] = s;
  part[(size_t)(NCHUNK + chunk)*C + c] = ss;
}

__global__ void k_stats_fin(const float* __restrict__ part, int C,
      const float* __restrict__ g, const float* __restrict__ be,
      float* __restrict__ scale, float* __restrict__ shift) {
  int c = threadIdx.x;
  float s = 0.f, ss = 0.f;
  for (int ch = 0; ch < NCHUNK; ++ch) {
    s  += part[(size_t)ch*C + c];
    ss += part[(size_t)(NCHUNK+ch)*C + c];
  }
  float mu = s / (float)NR;
  float var = ss/(float)NR - mu*mu;
  float rs = 1.0f / sqrtf(var + EPS_BN);
  float sc = g[c]*rs;
  scale[c] = sc;
  shift[c] = be[c] - mu*sc;
}

// ---------------- h = bn(z); f = h/max(||h||,1e-12); sq = sum f^2 ----------------
__global__ __launch_bounds__(256) void k_h_f(float* __restrict__ h,
      float* __restrict__ f, float* __restrict__ sq,
      const float* __restrict__ scale, const float* __restrict__ shift) {
  int w = threadIdx.x >> 6, lane = threadIdx.x & 63;
  size_t row = (size_t)blockIdx.x*4 + w;
  float* hp = h + row*CC;
  float hv[3]; float s = 0.f;
  #pragma unroll
  for (int t = 0; t < 3; ++t) {
    int c = lane + 64*t;
    float v = hp[c]*scale[c] + shift[c];
    hv[t] = v; s += v*v;
  }
  #pragma unroll
  for (int o = 32; o; o >>= 1) s += __shfl_xor(s, o);
  float eta = fmaxf(sqrtf(s), 1e-12f);
  float fv[3]; float s2 = 0.f;
  #pragma unroll
  for (int t = 0; t < 3; ++t) { fv[t] = hv[t]/eta; s2 += fv[t]*fv[t]; }
  #pragma unroll
  for (int o = 32; o; o >>= 1) s2 += __shfl_xor(s2, o);
  #pragma unroll
  for (int t = 0; t < 3; ++t) {
    hp[lane + 64*t] = hv[t];
    f[row*CC + lane + 64*t] = fv[t];
  }
  if (lane == 0) sq[row] = s2;
}

// ---------------- fused pairwise distance + top-9 selection (per batch) ----------------
__global__ __launch_bounds__(256) void k_dist(const float* __restrict__ f,
     const float* __restrict__ sq, int* __restrict__ idxg) {
  __shared__ __align__(16) float As[64*68];
  __shared__ __align__(16) float Bs[64*68];
  __shared__ float dts[64*65];
  __shared__ float topD[64*9];
  __shared__ int   topI[64*9];
  __shared__ float worstS[64], sqa[64], sqb[64];
  int rt = blockIdx.x, b = blockIdx.y;
  int tid = threadIdx.x;
  int lane = tid & 63, wv = tid >> 6;
  int tc = tid & 15, tr = tid >> 4;
  const float4* fb4 = (const float4*)(f + (size_t)b*NN*CC);
  if (tid < 64) { sqa[tid] = sq[b*NN + rt*64 + tid]; worstS[tid] = 3.0e38f; }
  for (int q = tid; q < 64*9; q += 256) { topD[q] = 3.0e38f; topI[q] = 0; }

  for (int ct = 0; ct < 49; ++ct) {
    float acc[4][4];
    #pragma unroll
    for (int i = 0; i < 4; ++i)
      #pragma unroll
      for (int j = 0; j < 4; ++j) acc[i][j] = 0.f;
    if (tid < 64) sqb[tid] = sq[b*NN + ct*64 + tid];
    for (int kc = 0; kc < 3; ++kc) {
      __syncthreads();
      #pragma unroll
      for (int s = 0; s < 4; ++s) {
        int q = tid + 256*s;
        int row = q >> 4, kq = q & 15;
        ((float4*)As)[row*17 + kq] = fb4[(size_t)(rt*64 + row)*48 + kc*16 + kq];
        ((float4*)Bs)[row*17 + kq] = fb4[(size_t)(ct*64 + row)*48 + kc*16 + kq];
      }
      __syncthreads();
      #pragma unroll 4
      for (int k4 = 0; k4 < 16; ++k4) {
        float4 a[4], bv[4];
        #pragma unroll
        for (int i = 0; i < 4; ++i) a[i]  = ((const float4*)As)[(tr + 16*i)*17 + k4];
        #pragma unroll
        for (int j = 0; j < 4; ++j) bv[j] = ((const float4*)Bs)[(tc + 16*j)*17 + k4];
        #pragma unroll
        for (int i = 0; i < 4; ++i)
          #pragma unroll
          for (int j = 0; j < 4; ++j)
            acc[i][j] += a[i].x*bv[j].x + a[i].y*bv[j].y + a[i].z*bv[j].z + a[i].w*bv[j].w;
      }
    }
    // dist tile -> LDS
    #pragma unroll
    for (int i = 0; i < 4; ++i)
      #pragma unroll
      for (int j = 0; j < 4; ++j)
        dts[(tr+16*i)*65 + (tc+16*j)] = sqa[tr+16*i] + sqb[tc+16*j] - 2.f*acc[i][j];
    __syncthreads();
    // selection: wave wv owns rows wv*16 .. wv*16+15; columns in ascending order
    for (int rr = 0; rr < 16; ++rr) {
      int r = wv*16 + rr;
      float d = dts[r*65 + lane];
      int cg = ct*64 + lane;
      unsigned long long mask = __ballot(d < worstS[r]);
      while (mask) {
        int lb = __ffsll(mask) - 1;
        mask &= (mask - 1);
        float dc = __shfl(d, lb);
        int  ccx = __shfl(cg, lb);
        float wvv = topD[r*9]; int wp = 0;
        #pragma unroll
        for (int t = 1; t < 9; ++t) { float v = topD[r*9+t]; if (v > wvv) { wvv = v; wp = t; } }
        if (dc < wvv) {
          if (lane == 0) { topD[r*9+wp] = dc; topI[r*9+wp] = ccx; }
          float nw = dc;
          #pragma unroll
          for (int t = 0; t < 9; ++t) if (t != wp) nw = fmaxf(nw, topD[r*9+t]);
          if (lane == 0) worstS[r] = nw;
        }
      }
    }
  }
  __syncthreads();
  if (tid < 64) {
    size_t base = ((size_t)b*NN + rt*64 + tid)*KNN;
    #pragma unroll
    for (int t = 0; t < KNN; ++t) idxg[base + t] = topI[tid*9 + t];
  }
}

// ---------------- gather neighbors, rel = max_k h[idx_k] - h, interleave feat ----------------
__global__ __launch_bounds__(256) void k_gather(const float* __restrict__ h,
    const int* __restrict__ idxg, float* __restrict__ feat) {
  int w = threadIdx.x >> 6, lane = threadIdx.x & 63;
  size_t rg = (size_t)blockIdx.x*4 + w;
  int b = (int)(rg / NN);
  int n = (int)(rg % NN);
  const float* hb = h + (size_t)b*NN*CC;
  int j[KNN];
  #pragma unroll
  for (int t = 0; t < KNN; ++t) j[t] = idxg[rg*KNN + t];
  float2* featp = (float2*)feat;
  #pragma unroll
  for (int t = 0; t < 3; ++t) {
    int c = lane + 64*t;
    float self = hb[(size_t)n*CC + c];
    float m = -3.0e38f;
    #pragma unroll
    for (int k = 0; k < KNN; ++k) m = fmaxf(m, hb[(size_t)j[k]*CC + c]);
    featp[rg*CC + c] = make_float2(self, m - self);
  }
}

// ---------------- grouped conv: y[r][g*96+o] = sum_i feat[r][g*96+i]*wgc[g*96+o][i] + bgc ----------------
__global__ __launch_bounds__(256) void k_gconv(const float* __restrict__ feat,
   const float* __restrict__ wgc, const float* __restrict__ bgc, float* __restrict__ y) {
  __shared__ __align__(16) float Fs[64*100];
  __shared__ __align__(16) float Wsh[96*100];
  int rt = blockIdx.x, g = blockIdx.y;
  int tid = threadIdx.x, tc = tid & 15, tr = tid >> 4;
  const float4* f4p = (const float4*)feat;
  #pragma unroll
  for (int s = 0; s < 6; ++s) {
    int q = tid + 256*s; int r = q/24, kq = q - r*24;
    ((float4*)Fs)[r*25 + kq] = f4p[(size_t)(rt*64 + r)*96 + g*24 + kq];
  }
  #pragma unroll
  for (int s = 0; s < 9; ++s) {
    int q = tid + 256*s; int o = q/24, kq = q - o*24;
    ((float4*)Wsh)[o*25 + kq] = ((const float4*)wgc)[(size_t)(g*GI + o)*24 + kq];
  }
  __syncthreads();
  float acc[4][6] = {};
  #pragma unroll 4
  for (int k4 = 0; k4 < 24; ++k4) {
    float4 a[4], bv[6];
    #pragma unroll
    for (int i = 0; i < 4; ++i) a[i]  = ((const float4*)Fs)[(tr+16*i)*25 + k4];
    #pragma unroll
    for (int j = 0; j < 6; ++j) bv[j] = ((const float4*)Wsh)[(tc+16*j)*25 + k4];
    #pragma unroll
    for (int i = 0; i < 4; ++i)
      #pragma unroll
      for (int j = 0; j < 6; ++j)
        acc[i][j] += a[i].x*bv[j].x + a[i].y*bv[j].y + a[i].z*bv[j].z + a[i].w*bv[j].w;
  }
  #pragma unroll
  for (int j = 0; j < 6; ++j) {
    float bias = bgc[g*GI + tc + 16*j];
    #pragma unroll
    for (int i = 0; i < 4; ++i)
      y[(size_t)(rt*64 + tr + 16*i)*C2 + g*GI + tc + 16*j] = acc[i][j] + bias;
  }
}

// ---------------- bn + exact gelu, in place ----------------
__global__ void k_bn_gelu(float* __restrict__ y, const float* __restrict__ scale,
                          const float* __restrict__ shift) {
  size_t i = (size_t)blockIdx.x*blockDim.x + threadIdx.x;  // float4 index
  float4 v = ((float4*)y)[i];
  int c4 = (int)(i % 96);
  float4 sc = ((const float4*)scale)[c4], sh = ((const float4*)shift)[c4];
  float vv[4] = {v.x*sc.x+sh.x, v.y*sc.y+sh.y, v.z*sc.z+sh.z, v.w*sc.w+sh.w};
  #pragma unroll
  for (int t = 0; t < 4; ++t)
    vv[t] = 0.5f*vv[t]*(1.0f + erff(vv[t]*0.70710678118654752440f));
  v.x = vv[0]; v.y = vv[1]; v.z = vv[2]; v.w = vv[3];
  ((float4*)y)[i] = v;
}

// ---------------- fc2: op[r][c] = sum_k y2[r][k]*w2[c][k] + b2[c] ----------------
__global__ __launch_bounds__(256) void k_fc2(const float* __restrict__ y2,
    const float* __restrict__ w2, const float* __restrict__ b2, float* __restrict__ op) {
  __shared__ __align__(16) float As[64*68];
  __shared__ __align__(16) float Wsh[64*68];
  int rt = blockIdx.x, c0 = blockIdx.y*64;
  int tid = threadIdx.x, tc = tid & 15, tr = tid >> 4;
  float acc[4][4] = {};
  for (int kc = 0; kc < 6; ++kc) {
    __syncthreads();
    #pragma unroll
    for (int s = 0; s < 4; ++s) {
      int q = tid + 256*s;
      int r = q >> 4, kq = q & 15;
      ((float4*)As)[r*17 + kq]  = ((const float4*)y2)[(size_t)(rt*64 + r)*96 + kc*16 + kq];
      ((float4*)Wsh)[r*17 + kq] = ((const float4*)w2)[(size_t)(c0 + r)*96 + kc*16 + kq];
    }
    __syncthreads();
    #pragma unroll 4
    for (int k4 = 0; k4 < 16; ++k4) {
      float4 a[4], bv[4];
      #pragma unroll
      for (int i = 0; i < 4; ++i) a[i]  = ((const float4*)As)[(tr+16*i)*17 + k4];
      #pragma unroll
      for (int j = 0; j < 4; ++j) bv[j] = ((const float4*)Wsh)[(tc+16*j)*17 + k4];
      #pragma unroll
      for (int i = 0; i < 4; ++i)
        #pragma unroll
        for (int j = 0; j < 4; ++j)
          acc[i][j] += a[i].x*bv[j].x + a[i].y*bv[j].y + a[i].z*bv[j].z + a[i].w*bv[j].w;
    }
  }
  #pragma unroll
  for (int j = 0; j < 4; ++j) {
    float bias = b2[c0 + tc + 16*j];
    #pragma unroll
    for (int i = 0; i < 4; ++i)
      op[(size_t)(rt*64 + tr + 16*i)*CC + c0 + tc + 16*j] = acc[i][j] + bias;
  }
}

// ---------------- final bn + residual + transpose to (B,C,N) ----------------
__global__ __launch_bounds__(256) void k_final(const float* __restrict__ op,
    const float* __restrict__ x, const float* __restrict__ scale,
    const float* __restrict__ shift, float* __restrict__ out) {
  __shared__ float t[32][33];
  int n0 = blockIdx.x*32, c0 = blockIdx.y*32, b = blockIdx.z;
  int tx = threadIdx.x, ty = threadIdx.y;
  #pragma unroll
  for (int s = 0; s < 4; ++s) {
    int r = ty + 8*s;
    int c = c0 + tx;
    t[r][tx] = op[((size_t)b*NN + n0 + r)*CC + c]*scale[c] + shift[c];
  }
  __syncthreads();
  #pragma unroll
  for (int s = 0; s < 4; ++s) {
    int c = ty + 8*s;
    size_t o = ((size_t)b*CC + c0 + c)*NN + n0 + tx;
    out[o] = t[tx][c] + x[o];
  }
}

extern "C" void kernel_launch(void* const* d_in, const int* in_sizes, int n_in,
                              void* d_out, int out_size, void* d_ws, size_t ws_size,
                              hipStream_t stream) {
  (void)in_sizes; (void)n_in; (void)out_size; (void)ws_size;
  const float* x   = (const float*)d_in[0];
  const float* w1  = (const float*)d_in[1];
  const float* b1  = (const float*)d_in[2];
  const float* g1  = (const float*)d_in[3];
  const float* be1 = (const float*)d_in[4];
  const float* wgc = (const float*)d_in[5];
  const float* bgc = (const float*)d_in[6];
  const float* g2  = (const float*)d_in[7];
  const float* be2 = (const float*)d_in[8];
  const float* w2  = (const float*)d_in[9];
  const float* b2  = (const float*)d_in[10];
  const float* g3  = (const float*)d_in[11];
  const float* be3 = (const float*)d_in[12];
  float* ws = (float*)d_ws;

  // Workspace layout (floats). op aliases h: h is dead after k_gather,
  // and k_fc2 (first writer of op) runs strictly later on the same stream.
  float* h    = ws;                        // 4,816,896  (z then h in place; later op)
  float* feat = ws + 4816896;              // 9,633,792  (f aliases first half; y in place)
  float* f    = feat;
  float* op   = ws;                        // alias of h region
  float* sq   = ws + 14450688;             // 25,088
  int*   idx  = (int*)(ws + 14475776);     // 225,792 ints
  float* part = ws + 14701568;             // 196,608
  float* st   = ws + 14898176;             // 1,536   (total 14,899,712 floats ≈ 59.6 MB)
  float* sc1 = st;        float* sh1 = st + 192;
  float* sc2 = st + 384;  float* sh2 = st + 768;
  float* sc3 = st + 1152; float* sh3 = st + 1344;
  float* out = (float*)d_out;

  k_fc1<<<dim3(49,3,8), 256, 0, stream>>>(x, w1, b1, h);
  k_stats_part<<<NCHUNK, CC, 0, stream>>>(h, CC, part);
  k_stats_fin<<<1, CC, 0, stream>>>(part, CC, g1, be1, sc1, sh1);
  k_h_f<<<NR/4, 256, 0, stream>>>(h, f, sq, sc1, sh1);
  k_dist<<<dim3(49,8), 256, 0, stream>>>(f, sq, idx);
  k_gather<<<NR/4, 256, 0, stream>>>(h, idx, feat);
  k_gconv<<<dim3(392,4), 256, 0, stream>>>(feat, wgc, bgc, feat);   // y in place
  k_stats_part<<<NCHUNK, C2, 0, stream>>>(feat, C2, part);
  k_stats_fin<<<1, C2, 0, stream>>>(part, C2, g2, be2, sc2, sh2);
  k_bn_gelu<<<9408, 256, 0, stream>>>(feat, sc2, sh2);
  k_fc2<<<dim3(392,3), 256, 0, stream>>>(feat, w2, b2, op);
  k_stats_part<<<NCHUNK, CC, 0, stream>>>(op, CC, part);
  k_stats_fin<<<1, CC, 0, stream>>>(part, CC, g3, be3, sc3, sh3);
  k_final<<<dim3(98,6,8), dim3(32,8), 0, stream>>>(op, x, sc3, sh3, out);
}